// Round 1
// baseline (68.622 us; speedup 1.0000x reference)
//
#include <hip/hip_runtime.h>

// Problem constants (from reference)
constexpr int Cc  = 224;   // channels
constexpr int Tt  = 224;   // time steps
constexpr int KS  = 13;    // gaussian kernel taps
constexpr int PAD = 6;     // (KS-1)/2
constexpr int TT  = 32;    // time tile width (224 = 7*32)
constexpr int LDW = TT + 1;          // LDS row stride (33) -> conflict-free scalar access
constexpr int ROWS = Cc + 2 * PAD;   // 236 rows incl. zero halo
constexpr int BDIM = 256;

__global__ __launch_bounds__(BDIM)
void cgss_snn_kernel(const float* __restrict__ x,
                     const float* __restrict__ wp,
                     float* __restrict__ out)
{
    __shared__ float kern[KS];
    __shared__ float tile[ROWS * LDW];   // input x tile (channels+halo) x (time)
    __shared__ float otile[Cc * LDW];    // spike output tile

    const int tid = threadIdx.x;
    const int b   = blockIdx.x;
    const long long base = (long long)b * Cc * Tt;

    // Zero the 12 halo rows once (they are never overwritten afterwards).
    for (int idx = tid; idx < 2 * PAD * LDW; idx += BDIM) {
        int row = idx / LDW;
        int col = idx - row * LDW;
        int r   = (row < PAD) ? row : (row + Cc);   // rows 0..5 and 230..235
        tile[r * LDW + col] = 0.0f;
    }

    // Gaussian kernel from scalar w (mirrors reference fp32 math).
    if (tid == 0) {
        float w  = wp[0];
        float wc = fminf(fmaxf(w, 0.4f), 10.0f);
        float norm = 0.0f;
        const float step = 120.0f / 129.0f;          // linspace(-60,60,130) step
        for (int j = 0; j < KS * 10; ++j) {
            float r = -60.0f + (float)j * step;
            float z = r / wc;
            norm += expf(-0.5f * z * z);
        }
        for (int i = 0; i < KS; ++i) {
            float r = (float)(i - PAD);
            float z = r / wc;
            kern[i] = expf(-0.5f * z * z) / norm;
        }
    }
    __syncthreads();

    float kr[KS];
#pragma unroll
    for (int i = 0; i < KS; ++i) kr[i] = kern[i];

    const int c = tid;          // channel owned by this thread (tid < 224)
    float mem = 0.0f;           // LIF membrane, carried across time tiles
    float rst = 0.0f;           // previous step's spike (== reset indicator)

    for (int t0 = 0; t0 < Tt; t0 += TT) {
        // ---- stage x[b, :, t0:t0+TT] into LDS (coalesced float4 reads) ----
#pragma unroll
        for (int r = 0; r < (Cc * TT / 4) / BDIM; ++r) {  // 7 iterations
            int q  = r * BDIM + tid;       // 0..1791
            int cc = q >> 3;               // channel 0..223
            int tq = (q & 7) << 2;         // time offset 0,4,...,28
            const float4 v = *reinterpret_cast<const float4*>(
                x + base + (long long)cc * Tt + t0 + tq);
            int la = (cc + PAD) * LDW + tq;
            tile[la + 0] = v.x; tile[la + 1] = v.y;
            tile[la + 2] = v.z; tile[la + 3] = v.w;
        }
        __syncthreads();

        // ---- per-channel conv + LIF scan over this time tile ----
        if (c < Cc) {
#pragma unroll 4
            for (int t = 0; t < TT; ++t) {
                float acc = 0.0f;
#pragma unroll
                for (int i = 0; i < KS; ++i)
                    acc += kr[i] * tile[(c + i) * LDW + t];
                float xv = tile[(c + PAD) * LDW + t];
                // I = x - relu(x - x_mean)  (== min(x, x_mean), ref op order)
                float d  = xv - acc;
                float rl = d > 0.0f ? d : 0.0f;
                float I  = xv - rl;
                mem = 0.97f * mem + I - rst;        // rst = prev spike * THR
                float spk = (mem > 1.0f) ? 1.0f : 0.0f;
                rst = spk;
                otile[c * LDW + t] = spk;
            }
        }
        __syncthreads();

        // ---- coalesced write of spikes ----
        for (int q = tid; q < Cc * TT; q += BDIM) {
            int cc = q >> 5;
            int t  = q & 31;
            out[base + (long long)cc * Tt + t0 + t] = otile[cc * LDW + t];
        }
        __syncthreads();   // before next tile overwrites LDS
    }
}

extern "C" void kernel_launch(void* const* d_in, const int* in_sizes, int n_in,
                              void* d_out, int out_size, void* d_ws, size_t ws_size,
                              hipStream_t stream)
{
    const float* x  = (const float*)d_in[0];
    const float* w  = (const float*)d_in[1];
    float* out      = (float*)d_out;
    const int B = in_sizes[0] / (Cc * Tt);   // 512
    cgss_snn_kernel<<<B, BDIM, 0, stream>>>(x, w, out);
}

// Round 2
// 67.259 us; speedup vs baseline: 1.0203x; 1.0203x over previous
//
#include <hip/hip_runtime.h>

constexpr int Cc = 224;             // channels
constexpr int Tt = 224;             // time steps
constexpr int TT = 32;              // time tile width
constexpr int NTILE = Tt / TT;      // 7
constexpr int SROWS = 128;          // slab rows per wave (112 channels + halo/pad)
constexpr int SLABWORDS = SROWS * TT;  // 4096 floats = 16 KiB per buffer
constexpr int BDIM = 128;           // 2 waves; each wave = half a batch

// async 16B-per-lane global->LDS (dest = wave-uniform base + lane*16)
#define GLDS16(src, dst) __builtin_amdgcn_global_load_lds( \
    (const __attribute__((address_space(1))) unsigned int*)(src), \
    (__attribute__((address_space(3))) unsigned int*)(dst), 16, 0, 0)

__global__ __launch_bounds__(BDIM)
void cgss_snn_kernel(const float* __restrict__ x,
                     const float* __restrict__ wp,
                     float* __restrict__ out)
{
    // [wave][buf][slab] : 2*2*16KiB = 64 KiB -> 2 blocks/CU
    __shared__ float lds[2 * 2 * SLABWORDS];

    const int tid = threadIdx.x;
    const int w   = tid >> 6;          // wave id: channels [112w, 112w+112)
    const int l   = tid & 63;
    const int b   = blockIdx.x;

    float* slab = &lds[w * 2 * SLABWORDS];
    const long long bofs = (long long)b * Cc * Tt;
    const float* xb = x + bofs;
    float*       ob = out + bofs;

    const int cbase = 112 * w - 8;     // slab row r holds channel cbase + r

    // ---- zero the halo chunk (rows with no valid channel) in both buffers ----
    {
        const int zj = (w == 0) ? 0 : 15;   // w0: c -8..-1 ; w1: c 224..231
        float4 z = make_float4(0.f, 0.f, 0.f, 0.f);
        *reinterpret_cast<float4*>(&slab[0 * SLABWORDS + zj * 256 + l * 4]) = z;
        *reinterpret_cast<float4*>(&slab[1 * SLABWORDS + zj * 256 + l * 4]) = z;
    }

    // ---- async stage of one time tile: 15 x 1KiB chunks (8 rows each) ----
    // LDS layout: word(r,t) = r*32 + (( (t>>2) ^ ((r>>1)&7) )<<2) + (t&3)
    // (16B-chunk XOR swizzle, applied by pre-swizzling the global source)
    const int jbeg = (w == 0) ? 1 : 0;
    const int jend = (w == 0) ? 16 : 15;
    const int srow = l >> 3;           // row within chunk
    const int sc   = l & 7;            // stored 16B slot within row

    auto stage = [&](int buf, int t0) {
        for (int j = jbeg; j < jend; ++j) {
            int r  = 8 * j + srow;
            int tq = sc ^ ((r >> 1) & 7);          // t-quad this slot holds
            const float* src = xb + (cbase + r) * Tt + t0 + tq * 4;
            float* dst = &slab[buf * SLABWORDS + j * 256];
            GLDS16(src, dst);
        }
    };

    stage(0, 0);   // tile 0 in flight while we compute the gaussian kernel

    // ---- gaussian kernel (arithmetic identical to verified round-1 code) ----
    float kr[13];
    {
        float wv = wp[0];
        float wc = fminf(fmaxf(wv, 0.4f), 10.0f);
        float norm = 0.0f;
        const float step = 120.0f / 129.0f;
        for (int j = 0; j < 130; ++j) {
            float r = -60.0f + (float)j * step;
            float z = r / wc;
            norm += expf(-0.5f * z * z);
        }
        for (int i = 0; i < 13; ++i) {
            float r = (float)(i - 6);
            float z = r / wc;
            kr[i] = expf(-0.5f * z * z) / norm;
        }
    }

    float mem0 = 0.f, mem1 = 0.f, rst0 = 0.f, rst1 = 0.f;
    const int c0 = 112 * w + 2 * l;    // first owned channel (valid when l < 56)
    int buf = 0;

    asm volatile("s_waitcnt vmcnt(0)" ::: "memory");
    __builtin_amdgcn_sched_barrier(0);

    for (int tile = 0; tile < NTILE; ++tile) {
        const int t0 = tile * TT;
        if (tile < NTILE - 1) stage(buf ^ 1, t0 + TT);   // overlap next-tile HBM

        if (l < 56) {
            const float* sb = &slab[buf * SLABWORDS];
            const int rb = 2 * l + 2;                    // slab row of val[0]
#pragma unroll 2
            for (int tq = 0; tq < 8; ++tq) {
                float4 val[14];
#pragma unroll
                for (int k = 0; k < 14; ++k) {
                    int r = rb + k;
                    int q = tq ^ ((r >> 1) & 7);
                    val[k] = *reinterpret_cast<const float4*>(&sb[r * 32 + q * 4]);
                }
                float4 a0 = make_float4(0,0,0,0), a1 = make_float4(0,0,0,0);
#pragma unroll
                for (int i = 0; i < 13; ++i) {
                    float kk = kr[i];
                    a0.x += kk * val[i].x;    a0.y += kk * val[i].y;
                    a0.z += kk * val[i].z;    a0.w += kk * val[i].w;
                    a1.x += kk * val[i+1].x;  a1.y += kk * val[i+1].y;
                    a1.z += kk * val[i+1].z;  a1.w += kk * val[i+1].w;
                }
                float4 s0, s1;
                {
                    const float* xv = (const float*)&val[6];
                    const float* av = (const float*)&a0;
                    float*       sv = (float*)&s0;
#pragma unroll
                    for (int s = 0; s < 4; ++s) {
                        float d  = xv[s] - av[s];
                        float rl = d > 0.0f ? d : 0.0f;
                        float I  = xv[s] - rl;
                        mem0 = 0.97f * mem0 + I - rst0;
                        float spk = (mem0 > 1.0f) ? 1.0f : 0.0f;
                        rst0 = spk;
                        sv[s] = spk;
                    }
                }
                {
                    const float* xv = (const float*)&val[7];
                    const float* av = (const float*)&a1;
                    float*       sv = (float*)&s1;
#pragma unroll
                    for (int s = 0; s < 4; ++s) {
                        float d  = xv[s] - av[s];
                        float rl = d > 0.0f ? d : 0.0f;
                        float I  = xv[s] - rl;
                        mem1 = 0.97f * mem1 + I - rst1;
                        float spk = (mem1 > 1.0f) ? 1.0f : 0.0f;
                        rst1 = spk;
                        sv[s] = spk;
                    }
                }
                const int t = t0 + tq * 4;
                *reinterpret_cast<float4*>(&ob[(long long)c0 * Tt + t])       = s0;
                *reinterpret_cast<float4*>(&ob[(long long)(c0 + 1) * Tt + t]) = s1;
            }
        }

        // wave-private pipeline sync: next tile's async loads (and our stores) done
        asm volatile("s_waitcnt vmcnt(0)" ::: "memory");
        __builtin_amdgcn_sched_barrier(0);
        buf ^= 1;
    }
}

extern "C" void kernel_launch(void* const* d_in, const int* in_sizes, int n_in,
                              void* d_out, int out_size, void* d_ws, size_t ws_size,
                              hipStream_t stream)
{
    const float* x  = (const float*)d_in[0];
    const float* w  = (const float*)d_in[1];
    float* out      = (float*)d_out;
    const int B = in_sizes[0] / (Cc * Tt);   // 512
    cgss_snn_kernel<<<B, BDIM, 0, stream>>>(x, w, out);
}